// Round 1
// baseline (785.238 us; speedup 1.0000x reference)
//
#include <hip/hip_runtime.h>

// ---------------------------------------------------------------------------
// QuantizedLoRALinear: y = x @ W_dq^T + 0.25*(x@A^T)@B^T
//   Fold LoRA into weight: W_eff[o][i] = NF4[q[o][i]]*scale + 0.25*sum_r B[o][r]*A[r][i]
//   Then one bf16 GEMM (M=8192, N=4096, K=4096), m97-structure (128^2 tile, BK=32).
// ---------------------------------------------------------------------------

#define DIN   4096
#define DOUT  4096
#define RNK   64
#define MTOT  8192          // 4*2048
#define LORA_SCALE 0.25f

#define BM 128
#define BN 128
#define BK 32

typedef unsigned short u16;
typedef __attribute__((ext_vector_type(8))) short bf16x8;   // 8 bf16 = 4 VGPR (MFMA A/B frag)
typedef __attribute__((ext_vector_type(4))) float f32x4;    // MFMA C/D frag

__constant__ float NF4C[16] = {
    -1.0f, -0.6962f, -0.5251f, -0.3949f, -0.2844f, -0.1848f,
    -0.0911f, 0.0f, 0.0796f, 0.1609f, 0.2461f, 0.3379f,
    0.4407f, 0.5626f, 0.723f, 1.0f};

// fp32 -> bf16 round-to-nearest-even (finite inputs only)
__device__ __forceinline__ u16 f2bf(float f) {
    unsigned int u = __float_as_uint(f);
    u += 0x7FFFu + ((u >> 16) & 1u);
    return (u16)(u >> 16);
}

// ---------------------------------------------------------------------------
// Kernel 1: x fp32 -> bf16 (vectorized: 8 floats in, 16B out per thread-iter)
// ---------------------------------------------------------------------------
__global__ __launch_bounds__(256) void cvt_x(const float* __restrict__ x,
                                             u16* __restrict__ xb, int n8) {
    int stride = gridDim.x * blockDim.x;
    for (int i = blockIdx.x * blockDim.x + threadIdx.x; i < n8; i += stride) {
        const float4* p = (const float4*)x + (size_t)i * 2;
        float4 a = p[0], b = p[1];
        union { u16 u[8]; int4 v; } o;
        o.u[0] = f2bf(a.x); o.u[1] = f2bf(a.y); o.u[2] = f2bf(a.z); o.u[3] = f2bf(a.w);
        o.u[4] = f2bf(b.x); o.u[5] = f2bf(b.y); o.u[6] = f2bf(b.z); o.u[7] = f2bf(b.w);
        *(int4*)(xb + (size_t)i * 8) = o.v;
    }
}

// ---------------------------------------------------------------------------
// Kernel 2: W_eff[o][i] = NF4[q]*scale + 0.25 * sum_r B[o][r]*A[r][i]  -> bf16
//   grid = DOUT*2 blocks; block handles one o-row half (2048 i's, 8 per thread)
// ---------------------------------------------------------------------------
__global__ __launch_bounds__(256) void build_weff(const int* __restrict__ q,
                                                  const float* __restrict__ wscale,
                                                  const float* __restrict__ lA,
                                                  const float* __restrict__ lB,
                                                  u16* __restrict__ W) {
    int o  = blockIdx.x >> 1;
    int i0 = ((blockIdx.x & 1) << 11) + (threadIdx.x << 3);
    float acc[8] = {0.f, 0.f, 0.f, 0.f, 0.f, 0.f, 0.f, 0.f};
    const float* Bo = lB + (size_t)o * RNK;
#pragma unroll 8
    for (int r = 0; r < RNK; ++r) {
        float bv = Bo[r];                                // block-uniform (scalar)
        const float4* ap = (const float4*)(lA + (size_t)r * DIN + i0);
        float4 a0 = ap[0], a1 = ap[1];
        acc[0] = fmaf(bv, a0.x, acc[0]); acc[1] = fmaf(bv, a0.y, acc[1]);
        acc[2] = fmaf(bv, a0.z, acc[2]); acc[3] = fmaf(bv, a0.w, acc[3]);
        acc[4] = fmaf(bv, a1.x, acc[4]); acc[5] = fmaf(bv, a1.y, acc[5]);
        acc[6] = fmaf(bv, a1.z, acc[6]); acc[7] = fmaf(bv, a1.w, acc[7]);
    }
    float ws = wscale[0];
    const int4* qp = (const int4*)(q + (size_t)o * DIN + i0);
    int4 q0 = qp[0], q1 = qp[1];
    union { u16 u[8]; int4 v; } out;
    out.u[0] = f2bf(fmaf(LORA_SCALE, acc[0], NF4C[q0.x] * ws));
    out.u[1] = f2bf(fmaf(LORA_SCALE, acc[1], NF4C[q0.y] * ws));
    out.u[2] = f2bf(fmaf(LORA_SCALE, acc[2], NF4C[q0.z] * ws));
    out.u[3] = f2bf(fmaf(LORA_SCALE, acc[3], NF4C[q0.w] * ws));
    out.u[4] = f2bf(fmaf(LORA_SCALE, acc[4], NF4C[q1.x] * ws));
    out.u[5] = f2bf(fmaf(LORA_SCALE, acc[5], NF4C[q1.y] * ws));
    out.u[6] = f2bf(fmaf(LORA_SCALE, acc[6], NF4C[q1.z] * ws));
    out.u[7] = f2bf(fmaf(LORA_SCALE, acc[7], NF4C[q1.w] * ws));
    *(int4*)(W + (size_t)o * DIN + i0) = out.v;
}

// ---------------------------------------------------------------------------
// Kernel 3: C[m][n] = sum_k X[m][k]*W[n][k], bf16 in / f32 out.
//   m97 structure: 128x128 tile, BK=32, 256 thr (4 waves, 2x2), 4x4 16x16x32
//   frags/wave, global_load_lds width-16 staging, 2 barriers per K-step.
// ---------------------------------------------------------------------------
__global__ __launch_bounds__(256) void gemm_bt(const u16* __restrict__ X,
                                               const u16* __restrict__ W,
                                               float* __restrict__ C,
                                               int M, int N, int K) {
    __shared__ u16 As[BM * BK];   // [128][32] row-major, 8 KiB
    __shared__ u16 Bs[BN * BK];   // [128][32] row-major, 8 KiB

    // bijective XCD swizzle (gridDim.x % 8 == 0 here)
    int nwg = gridDim.x;
    int cpx = nwg >> 3;
    int bid = blockIdx.x;
    int swz = (bid & 7) * cpx + (bid >> 3);
    int ntn = N / BN;
    int tm = swz / ntn, tn = swz % ntn;

    int tid  = threadIdx.x;
    int lane = tid & 63;
    int wid  = tid >> 6;          // 0..3
    int wr   = wid >> 1;          // wave row (0..1) -> 64-row band
    int wc   = wid & 1;           // wave col (0..1) -> 64-col band

    f32x4 acc[4][4] = {};

    const u16* Abase = X + (size_t)tm * BM * K;
    const u16* Bbase = W + (size_t)tn * BN * K;

    // staging geometry: 1 KiB chunk = 16 rows x 4 (16B cols); lane -> (row, col)
    int r_in = lane >> 2;         // 0..15
    int c_in = lane & 3;          // 0..3 (x8 elements)

    // fragment geometry (mfma_f32_16x16x32_bf16): lane&15 = row/col, (lane>>4)*8 = k
    int fr = lane & 15;
    int fk = (lane >> 4) << 3;

    int nkt = K / BK;
    for (int kt = 0; kt < nkt; ++kt) {
        int k0 = kt * BK;
        __syncthreads();          // LDS safe to overwrite
#pragma unroll
        for (int c = 0; c < 2; ++c) {
            int ch  = wid * 2 + c;           // wave-uniform chunk id (0..7)
            int row = ch * 16 + r_in;
            __builtin_amdgcn_global_load_lds(
                (const __attribute__((address_space(1))) void*)(Abase + (size_t)row * K + k0 + c_in * 8),
                (__attribute__((address_space(3))) void*)(As + ch * 512), 16, 0, 0);
            __builtin_amdgcn_global_load_lds(
                (const __attribute__((address_space(1))) void*)(Bbase + (size_t)row * K + k0 + c_in * 8),
                (__attribute__((address_space(3))) void*)(Bs + ch * 512), 16, 0, 0);
        }
        __syncthreads();          // compiler drains vmcnt(0) before s_barrier

        bf16x8 af[4], bfr[4];
#pragma unroll
        for (int i = 0; i < 4; ++i)
            af[i] = *(const bf16x8*)(As + (wr * 64 + i * 16 + fr) * BK + fk);
#pragma unroll
        for (int j = 0; j < 4; ++j)
            bfr[j] = *(const bf16x8*)(Bs + (wc * 64 + j * 16 + fr) * BK + fk);
#pragma unroll
        for (int i = 0; i < 4; ++i)
#pragma unroll
            for (int j = 0; j < 4; ++j)
                acc[i][j] = __builtin_amdgcn_mfma_f32_16x16x32_bf16(af[i], bfr[j], acc[i][j], 0, 0, 0);
    }

    // C/D layout (m89-verified): col = lane&15, row = (lane>>4)*4 + reg
    int rq  = (lane >> 4) << 2;
    int col = lane & 15;
    size_t crow0 = (size_t)tm * BM + wr * 64;
    size_t ccol0 = (size_t)tn * BN + wc * 64;
#pragma unroll
    for (int i = 0; i < 4; ++i)
#pragma unroll
        for (int j = 0; j < 4; ++j) {
            float* cp = C + (crow0 + i * 16 + rq) * N + ccol0 + j * 16 + col;
#pragma unroll
            for (int r = 0; r < 4; ++r)
                cp[(size_t)r * N] = acc[i][j][r];
        }
}

// ---------------------------------------------------------------------------
extern "C" void kernel_launch(void* const* d_in, const int* in_sizes, int n_in,
                              void* d_out, int out_size, void* d_ws, size_t ws_size,
                              hipStream_t stream) {
    const float* x  = (const float*)d_in[0];   // [4,2048,4096] f32
    const int*   qw = (const int*)d_in[1];     // [4096,4096] int32 in [0,16)
    const float* ws = (const float*)d_in[2];   // [1] f32
    const float* lA = (const float*)d_in[3];   // [64,4096] f32
    const float* lB = (const float*)d_in[4];   // [4096,64] f32
    float* out = (float*)d_out;                // [4,2048,4096] f32

    u16* Weff = (u16*)d_ws;                                      // 32 MiB
    u16* Xbf  = (u16*)((char*)d_ws + (size_t)DOUT * DIN * 2);    // 64 MiB

    cvt_x<<<4096, 256, 0, stream>>>(x, Xbf, MTOT * DIN / 8);
    build_weff<<<DOUT * 2, 256, 0, stream>>>(qw, ws, lA, lB, Weff);
    gemm_bt<<<(MTOT / BM) * (DOUT / BN), 256, 0, stream>>>(Xbf, Weff, out, MTOT, DOUT, DIN);
}

// Round 3
// 530.841 us; speedup vs baseline: 1.4792x; 1.4792x over previous
//
#include <hip/hip_runtime.h>

// ---------------------------------------------------------------------------
// QuantizedLoRALinear: y = x @ W_dq^T + 0.25*(x@A^T)@B^T
//   Fold LoRA into weight: W_eff = NF4[q]*scale + 0.25*(B@A)  (bf16)
//   Then one bf16 GEMM (M=8192, N=4096, K=4096) using the 256^2 8-phase
//   template (T1 XCD swizzle + T2 LDS XOR swizzle + T3/T4 counted vmcnt +
//   T5 setprio). LDS 128 KiB dynamic, 512 threads / 8 waves.
// ---------------------------------------------------------------------------

#define DIN   4096
#define DOUT  4096
#define RNK   64
#define MTOT  8192
#define LORA_SCALE 0.25f

#define BM 256
#define BN 256
#define BK 64
#define NT (DIN / BK)          // 64 K-tiles

typedef unsigned short u16;
typedef __attribute__((ext_vector_type(8))) short bf16x8;   // 8 bf16 (4 VGPR)
typedef __attribute__((ext_vector_type(4))) float f32x4;    // MFMA C/D frag

__constant__ float NF4C[16] = {
    -1.0f, -0.6962f, -0.5251f, -0.3949f, -0.2844f, -0.1848f,
    -0.0911f, 0.0f, 0.0796f, 0.1609f, 0.2461f, 0.3379f,
    0.4407f, 0.5626f, 0.723f, 1.0f};

__device__ __forceinline__ u16 f2bf(float f) {          // RNE fp32->bf16
    unsigned int u = __float_as_uint(f);
    u += 0x7FFFu + ((u >> 16) & 1u);
    return (u16)(u >> 16);
}

// ---------------------------------------------------------------------------
// Kernel 1: x fp32 -> bf16
// ---------------------------------------------------------------------------
__global__ __launch_bounds__(256) void cvt_x(const float* __restrict__ x,
                                             u16* __restrict__ xb, int n8) {
    int stride = gridDim.x * blockDim.x;
    for (int i = blockIdx.x * blockDim.x + threadIdx.x; i < n8; i += stride) {
        const float4* p = (const float4*)x + (size_t)i * 2;
        float4 a = p[0], b = p[1];
        union { u16 u[8]; int4 v; } o;
        o.u[0] = f2bf(a.x); o.u[1] = f2bf(a.y); o.u[2] = f2bf(a.z); o.u[3] = f2bf(a.w);
        o.u[4] = f2bf(b.x); o.u[5] = f2bf(b.y); o.u[6] = f2bf(b.z); o.u[7] = f2bf(b.w);
        *(int4*)(xb + (size_t)i * 8) = o.v;
    }
}

// ---------------------------------------------------------------------------
// Kernel 2 (tiled): W_eff[o][i] = NF4[q]*scale + 0.25*sum_r B[o][r]*A[r][i]
//   Block: 8 o-rows x 2048 i. B-panel (8x64) in LDS; A row reused by 8 o's.
//   A-traffic 8x lower than v1 (512 MB L2 total).
// ---------------------------------------------------------------------------
__global__ __launch_bounds__(256) void build_weff(const int* __restrict__ q,
                                                  const float* __restrict__ wscale,
                                                  const float* __restrict__ lA,
                                                  const float* __restrict__ lB,
                                                  u16* __restrict__ W) {
    __shared__ float Bsh[8 * RNK];                 // 2 KiB
    int og   = blockIdx.x >> 1;
    int half = blockIdx.x & 1;
    int o0   = og << 3;
    int i0   = (half << 11) + (threadIdx.x << 3);

    if (threadIdx.x < 128) {                       // 8 rows x 64 = 512 floats
        float4 v = *(const float4*)(lB + (size_t)o0 * RNK + threadIdx.x * 4);
        *(float4*)(Bsh + threadIdx.x * 4) = v;
    }
    __syncthreads();

    float acc[8][8] = {};
#pragma unroll 2
    for (int r = 0; r < RNK; ++r) {
        const float4* ap = (const float4*)(lA + (size_t)r * DIN + i0);
        float4 a0 = ap[0], a1 = ap[1];
        float av[8] = {a0.x, a0.y, a0.z, a0.w, a1.x, a1.y, a1.z, a1.w};
#pragma unroll
        for (int oo = 0; oo < 8; ++oo) {
            float bv = Bsh[oo * RNK + r];          // broadcast, conflict-free
#pragma unroll
            for (int k = 0; k < 8; ++k) acc[oo][k] = fmaf(bv, av[k], acc[oo][k]);
        }
    }

    float ws = wscale[0];
#pragma unroll
    for (int oo = 0; oo < 8; ++oo) {
        int o = o0 + oo;
        const int4* qp = (const int4*)(q + (size_t)o * DIN + i0);
        int4 q0 = qp[0], q1 = qp[1];
        union { u16 u[8]; int4 v; } out;
        out.u[0] = f2bf(fmaf(LORA_SCALE, acc[oo][0], NF4C[q0.x] * ws));
        out.u[1] = f2bf(fmaf(LORA_SCALE, acc[oo][1], NF4C[q0.y] * ws));
        out.u[2] = f2bf(fmaf(LORA_SCALE, acc[oo][2], NF4C[q0.z] * ws));
        out.u[3] = f2bf(fmaf(LORA_SCALE, acc[oo][3], NF4C[q0.w] * ws));
        out.u[4] = f2bf(fmaf(LORA_SCALE, acc[oo][4], NF4C[q1.x] * ws));
        out.u[5] = f2bf(fmaf(LORA_SCALE, acc[oo][5], NF4C[q1.y] * ws));
        out.u[6] = f2bf(fmaf(LORA_SCALE, acc[oo][6], NF4C[q1.z] * ws));
        out.u[7] = f2bf(fmaf(LORA_SCALE, acc[oo][7], NF4C[q1.w] * ws));
        *(int4*)(W + (size_t)o * DIN + i0) = out.v;
    }
}

// ---------------------------------------------------------------------------
// Kernel 3: 256^2 8-phase bf16 GEMM, C[m][n] = sum_k X[m][k]*W[n][k].
//   8 waves (2Mx4N), per-wave 128x64 out = acc[8][4] 16x16 frags.
//   LDS: As/Bs x 2 parities, [256][64] bf16 each (32 KiB), XOR-swizzled
//   (byte ^= (row&7)<<4) via inverse-swizzled global source (rule #21).
//   Per K-tile: 4 phases x {ds_read || stage-issue || 16 MFMA}, one counted
//   vmcnt(4) per tile (never 0 in loop). B staged t+1 (opp parity),
//   A staged t+2 (same parity, after phase-3 reads complete).
//   Ledger: enter tile with 4 in flight (A(t+1)); +2 (p1) +2 (p2) +4 (p4)
//   = 12; vmcnt(4) retires A(t+1)+B(t+1), leaves A(t+2) in flight.
// ---------------------------------------------------------------------------
#define STAGE(gptr, lbase)                                                        \
    {                                                                             \
        _Pragma("unroll")                                                         \
        for (int q_ = 0; q_ < 2; ++q_) {                                          \
            int idx_ = q_ * 512 + tid;                                            \
            int row_ = idx_ >> 3;                                                 \
            int c_   = (idx_ & 7) ^ (row_ & 7);   /* inverse swizzle on source */ \
            __builtin_amdgcn_global_load_lds(                                     \
                (const __attribute__((address_space(1))) void*)((gptr) + (size_t)row_ * K + c_ * 8), \
                (__attribute__((address_space(3))) void*)((lbase) + idx_ * 16),   \
                16, 0, 0);                                                        \
        }                                                                         \
    }

// rule #18: inline-asm waitcnt does NOT order register-only MFMA; fence with
// sched_barrier(0) immediately after.
#define WAIT_LGKM0_FENCED()                                   \
    asm volatile("s_waitcnt lgkmcnt(0)" ::: "memory");        \
    __builtin_amdgcn_sched_barrier(0)

__global__ __launch_bounds__(512, 2) void gemm8p(const u16* __restrict__ X,
                                                 const u16* __restrict__ Wt,
                                                 float* __restrict__ C) {
    extern __shared__ char smem[];
    char* As0 = smem;                  // A parity 0 (tiles 0,2,4,..)
    char* As1 = smem + 32768;          // A parity 1
    char* Bs0 = smem + 65536;
    char* Bs1 = smem + 98304;

    const int K = DIN, N = DOUT;

    // T1: bijective XCD swizzle (gridDim.x = 512, %8 == 0)
    int bid = blockIdx.x;
    int cpx = gridDim.x >> 3;
    int swz = (bid & 7) * cpx + (bid >> 3);
    int ntn = N / BN;
    int tm = swz / ntn, tn = swz % ntn;

    int tid  = threadIdx.x;
    int lane = tid & 63;
    int wid  = tid >> 6;
    int wr   = wid >> 2;               // 0..1 -> 128-row half
    int wc   = wid & 3;                // 0..3 -> 64-col strip
    int fr   = lane & 15;
    int kqo  = (lane >> 4) << 4;       // k-quarter byte offset
    int swzc = (lane & 7) << 4;        // T2 read-side swizzle (== (row&7)<<4)

    const u16* Ab = X  + (size_t)tm * BM * K;
    const u16* Bb = Wt + (size_t)tn * BN * K;

    f32x4 acc[8][4] = {};
    bf16x8 af[4][2], bf0[2][2], bf1[2][2];

    // ---- prologue: A(0),B(0) -> parity0 ; A(1) -> parity1 ; 12 loads issued
    STAGE(Ab,                      As0);
    STAGE(Ab + (size_t)128 * K,    As0 + 16384);
    STAGE(Bb,                      Bs0);
    STAGE(Bb + (size_t)128 * K,    Bs0 + 16384);
    STAGE(Ab + BK,                 As1);
    STAGE(Ab + (size_t)128 * K + BK, As1 + 16384);
    asm volatile("s_waitcnt vmcnt(4)" ::: "memory");   // tile-0's 8 arrived
    __builtin_amdgcn_sched_barrier(0);
    __builtin_amdgcn_s_barrier();

    for (int t = 0; t < NT; ++t) {
        int cur = t & 1;
        char* Ac = cur ? As1 : As0;
        char* Bc = cur ? Bs1 : Bs0;
        char* Bn = cur ? Bs0 : Bs1;
        int k1 = ((t + 1) & (NT - 1)) * BK;    // wrap: dead-write, race-free
        int k2 = ((t + 2) & (NT - 1)) * BK;

        // ===== phase 1: read A m0-3 + B n0-1 ; stage B(t+1) h0 =====
#pragma unroll
        for (int i = 0; i < 4; ++i) {
            int row = wr * 128 + i * 16 + fr;
#pragma unroll
            for (int kk = 0; kk < 2; ++kk)
                af[i][kk] = *(const bf16x8*)(Ac + ((((row << 7) + (kk << 6) + kqo)) ^ swzc));
        }
#pragma unroll
        for (int j = 0; j < 2; ++j) {
            int row = wc * 64 + j * 16 + fr;
#pragma unroll
            for (int kk = 0; kk < 2; ++kk)
                bf0[j][kk] = *(const bf16x8*)(Bc + ((((row << 7) + (kk << 6) + kqo)) ^ swzc));
        }
        STAGE(Bb + k1, Bn);
        __builtin_amdgcn_s_barrier();
        WAIT_LGKM0_FENCED();
        __builtin_amdgcn_s_setprio(1);
#pragma unroll
        for (int kk = 0; kk < 2; ++kk)
#pragma unroll
            for (int i = 0; i < 4; ++i)
#pragma unroll
                for (int j = 0; j < 2; ++j)
                    acc[i][j] = __builtin_amdgcn_mfma_f32_16x16x32_bf16(af[i][kk], bf0[j][kk], acc[i][j], 0, 0, 0);
        __builtin_amdgcn_s_setprio(0);
        __builtin_amdgcn_s_barrier();

        // ===== phase 2: read B n2-3 ; stage B(t+1) h1 =====
#pragma unroll
        for (int j = 0; j < 2; ++j) {
            int row = wc * 64 + (j + 2) * 16 + fr;
#pragma unroll
            for (int kk = 0; kk < 2; ++kk)
                bf1[j][kk] = *(const bf16x8*)(Bc + ((((row << 7) + (kk << 6) + kqo)) ^ swzc));
        }
        STAGE(Bb + (size_t)128 * K + k1, Bn + 16384);
        __builtin_amdgcn_s_barrier();
        WAIT_LGKM0_FENCED();
        __builtin_amdgcn_s_setprio(1);
#pragma unroll
        for (int kk = 0; kk < 2; ++kk)
#pragma unroll
            for (int i = 0; i < 4; ++i)
#pragma unroll
                for (int j = 0; j < 2; ++j)
                    acc[i][j + 2] = __builtin_amdgcn_mfma_f32_16x16x32_bf16(af[i][kk], bf1[j][kk], acc[i][j + 2], 0, 0, 0);
        __builtin_amdgcn_s_setprio(0);
        __builtin_amdgcn_s_barrier();

        // ===== phase 3: read A m4-7 (reuse af) ; no stage =====
#pragma unroll
        for (int i = 0; i < 4; ++i) {
            int row = wr * 128 + (i + 4) * 16 + fr;
#pragma unroll
            for (int kk = 0; kk < 2; ++kk)
                af[i][kk] = *(const bf16x8*)(Ac + ((((row << 7) + (kk << 6) + kqo)) ^ swzc));
        }
        __builtin_amdgcn_s_barrier();
        WAIT_LGKM0_FENCED();               // A-reads drained before p4 overwrites Ac
        __builtin_amdgcn_s_setprio(1);
#pragma unroll
        for (int kk = 0; kk < 2; ++kk)
#pragma unroll
            for (int i = 0; i < 4; ++i)
#pragma unroll
                for (int j = 0; j < 2; ++j)
                    acc[i + 4][j] = __builtin_amdgcn_mfma_f32_16x16x32_bf16(af[i][kk], bf0[j][kk], acc[i + 4][j], 0, 0, 0);
        __builtin_amdgcn_s_setprio(0);
        __builtin_amdgcn_s_barrier();

        // ===== phase 4: stage A(t+2) -> same parity (reads done) ; vmcnt(4) =====
        STAGE(Ab + k2, Ac);
        STAGE(Ab + (size_t)128 * K + k2, Ac + 16384);
        asm volatile("s_waitcnt vmcnt(4)" ::: "memory");   // A(t+1)+B(t+1) landed; A(t+2) in flight
        __builtin_amdgcn_sched_barrier(0);
        __builtin_amdgcn_s_barrier();
        __builtin_amdgcn_s_setprio(1);
#pragma unroll
        for (int kk = 0; kk < 2; ++kk)
#pragma unroll
            for (int i = 0; i < 4; ++i)
#pragma unroll
                for (int j = 0; j < 2; ++j)
                    acc[i + 4][j + 2] = __builtin_amdgcn_mfma_f32_16x16x32_bf16(af[i][kk], bf1[j][kk], acc[i + 4][j + 2], 0, 0, 0);
        __builtin_amdgcn_s_setprio(0);
        __builtin_amdgcn_s_barrier();
    }

    // ---- epilogue: C/D layout (m89): col = lane&15, row = (lane>>4)*4 + reg
    int rq  = (lane >> 4) << 2;
    int col = lane & 15;
    size_t crow0 = (size_t)tm * BM + wr * 128;
    size_t ccol0 = (size_t)tn * BN + wc * 64;
#pragma unroll
    for (int i = 0; i < 8; ++i)
#pragma unroll
        for (int j = 0; j < 4; ++j) {
            float* cp = C + (crow0 + i * 16 + rq) * N + ccol0 + j * 16 + col;
#pragma unroll
            for (int r = 0; r < 4; ++r)
                cp[(size_t)r * N] = acc[i][j][r];
        }
}

// ---------------------------------------------------------------------------
extern "C" void kernel_launch(void* const* d_in, const int* in_sizes, int n_in,
                              void* d_out, int out_size, void* d_ws, size_t ws_size,
                              hipStream_t stream) {
    const float* x  = (const float*)d_in[0];
    const int*   qw = (const int*)d_in[1];
    const float* ws = (const float*)d_in[2];
    const float* lA = (const float*)d_in[3];
    const float* lB = (const float*)d_in[4];
    float* out = (float*)d_out;

    u16* Weff = (u16*)d_ws;                                      // 32 MiB
    u16* Xbf  = (u16*)((char*)d_ws + (size_t)DOUT * DIN * 2);    // 64 MiB

    static_cast<void>(hipFuncSetAttribute(
        reinterpret_cast<const void*>(gemm8p),
        hipFuncAttributeMaxDynamicSharedMemorySize, 131072));

    cvt_x<<<4096, 256, 0, stream>>>(x, Xbf, MTOT * DIN / 8);
    build_weff<<<(DOUT / 8) * 2, 256, 0, stream>>>(qw, ws, lA, lB, Weff);
    gemm8p<<<(MTOT / BM) * (DOUT / BN), 512, 131072, stream>>>(Xbf, Weff, out);
}